// Round 21
// baseline (138.192 us; speedup 1.0000x reference)
//
#include <hip/hip_runtime.h>
#include <hip/hip_fp8.h>

#define F 128      // F_IN == H == 128
#define COUT 40
#define BSH 8      // 256 rows/cols per bucket
#define CAP 6144   // staging/csr slots per bucket
#define CH 8192    // edges per bucket-block in k_fat1
#define EPT 16     // edges per thread (CH/512)
#define NBLK 512   // blocks for k_gemm_red
#define CPAD 32    // ints per counter (128 B line)

typedef unsigned int  u32;
typedef unsigned short u16;
typedef __attribute__((ext_vector_type(8))) short short8;
typedef __attribute__((ext_vector_type(4))) float f32x4;

__device__ inline u32 bf16_rne(float f) {
  u32 u = __float_as_uint(f);
  u += 0x7FFFu + ((u >> 16) & 1u);
  return u >> 16;
}

#if defined(__has_builtin)
#if __has_builtin(__builtin_amdgcn_cvt_pk_fp8_f32) && __has_builtin(__builtin_amdgcn_cvt_f32_fp8)
#define HAS_FP8_BUILTIN 1
#endif
#endif

__device__ inline u32 fp8_pk4(float4 a) {
#ifdef HAS_FP8_BUILTIN
  u32 v = (u32)__builtin_amdgcn_cvt_pk_fp8_f32(a.x, a.y, 0, false);
  v = (u32)__builtin_amdgcn_cvt_pk_fp8_f32(a.z, a.w, (int)v, true);
  return v;
#else
  __hip_fp8x2_e4m3 lo(float2{a.x, a.y});
  __hip_fp8x2_e4m3 hi(float2{a.z, a.w});
  return (u32)lo.__x | ((u32)hi.__x << 16);
#endif
}

__device__ inline float2 fp8_dec2(u32 v) {
#ifdef HAS_FP8_BUILTIN
  return make_float2(__builtin_amdgcn_cvt_f32_fp8(v, 0),
                     __builtin_amdgcn_cvt_f32_fp8(v, 1));
#else
  __hip_fp8x2_e4m3 p;
  p.__x = (__hip_fp8x2_storage_t)(v & 0xFFFFu);
  float2 f = (float2)p;
  return make_float2(f.x, f.y);
#endif
}

// ---------------- zero padded bucket counters ----------------
__global__ void k_zero(int* __restrict__ bcountP, int* __restrict__ bcount2P, int n) {
  int i = blockIdx.x * blockDim.x + threadIdx.x;
  if (i < n) { bcountP[i] = 0; bcount2P[i] = 0; }
}

// ---- fat1: one-read dual bucket, SEQUENTIAL passes sharing one pay buffer ----
// blocks [0,nbB) = bucket; then 32 wt blocks; then cast blocks.
// payload: bits 0-16 = other node, 17-24 = key&255, 25-31 = bucket&127
__global__ void __launch_bounds__(512) k_fat1(
    const int* __restrict__ row, const int* __restrict__ col, int E,
    int* __restrict__ bcountP, unsigned* __restrict__ staging,
    int* __restrict__ bcount2P, unsigned* __restrict__ staging2,
    int nbuck, int nbB,
    const float4* __restrict__ X, uint2* __restrict__ Xq, int nvec,
    const float* __restrict__ W1, u16* __restrict__ W1T) {
  __shared__ u32 pay[CH];      // 32 KB (shared by both passes)
  __shared__ int hist[512];    // becomes inclusive scan in place
  __shared__ int lcur[512];
  __shared__ int gdelta[512];  // total LDS ~38 KB -> 4 blocks/CU
  int b = blockIdx.x;
  int t = threadIdx.x;

  if (b < nbB) {
    int base = b * CH;
    int n = E - base; if (n > CH) n = CH;
    int r[EPT], c[EPT];
#pragma unroll
    for (int j = 0; j < EPT; ++j) {
      int i = t + j * 512;
      if (i < n) { r[j] = row[base + i]; c[j] = col[base + i]; }
      else       { r[j] = -1; c[j] = -1; }
    }
#pragma unroll 1
    for (int p = 0; p < 2; ++p) {
      int* bcnt     = p ? bcount2P : bcountP;
      unsigned* stg = p ? staging2 : staging;
      if (p) __syncthreads();        // protect pay/hist reuse from pass 0 reads
      hist[t] = 0;
      __syncthreads();
#pragma unroll
      for (int j = 0; j < EPT; ++j) {
        int k = p ? c[j] : r[j];
        if (k >= 0) atomicAdd(&hist[k >> BSH], 1);
      }
      __syncthreads();
      int h = hist[t];
      for (int off = 1; off < 512; off <<= 1) {
        int x = hist[t];
        int y = (t >= off) ? hist[t - off] : 0;
        __syncthreads();
        hist[t] = x + y;
        __syncthreads();
      }
      if (t < nbuck) {
        int ex = hist[t] - h;
        int s = (h > 0) ? atomicAdd(&bcnt[t * CPAD], h) : 0;
        gdelta[t] = t * CAP + s - ex;
        lcur[t] = ex;
      }
      __syncthreads();
#pragma unroll
      for (int j = 0; j < EPT; ++j) {
        int k = p ? c[j] : r[j];
        int o = p ? r[j] : c[j];
        if (k >= 0) {
          int bk = k >> BSH;
          int s = atomicAdd(&lcur[bk], 1);
          pay[s] = ((u32)(bk & 127) << 25) | ((u32)(k & 255) << 17) | (u32)o;
        }
      }
      __syncthreads();
      int qa = hist[127], qb = hist[255], qc = hist[383];
#pragma unroll
      for (int j = 0; j < EPT; ++j) {
        int i = t + j * 512;
        if (i < n) {
          u32 pv = pay[i];
          int bk = (((i >= qa) + (i >= qb) + (i >= qc)) << 7) | (int)(pv >> 25);
          int dst = i + gdelta[bk];
          if (dst < (bk + 1) * CAP) stg[dst] = pv;
        }
      }
    }
  } else if (b < nbB + 32) {
    // cast+transpose W1 -> W1T (bf16 [H][K]); 32 blocks x 512 = 16384
    int i = (b - nbB) * 512 + t;
    int k = i >> 7, nn = i & 127;
    W1T[nn * 128 + k] = (u16)bf16_rne(W1[i]);
  } else {
    // cast X -> Xq (fp8 e4m3), 8 elems/thread
    int i = (b - nbB - 32) * 512 + t;
    if (i < nvec) {
      float4 a = X[2 * i], v = X[2 * i + 1];
      uint2 o;
      o.x = fp8_pk4(a);
      o.y = fp8_pk4(v);
      Xq[i] = o;
    }
  }
}

// ---- build: per-bucket CSR via LDS sort, coalesced csr writes, windowed ----
__global__ void __launch_bounds__(1024) k_build(
    const unsigned* __restrict__ staging,
    const int* __restrict__ bcountP,
    int2* __restrict__ rpd, float* __restrict__ dis,
    int* __restrict__ csr, int N) {
  __shared__ int cnt[256];
  __shared__ int cur[256];
  __shared__ u32 srt[CAP];   // 24 KB
  int b = blockIdx.x;
  int t = threadIdx.x;
  int r0 = b << BSH;
  int nrows = N - r0; if (nrows > 256) nrows = 256;
  int ecnt = bcountP[b * CPAD]; if (ecnt > CAP) ecnt = CAP;
  const unsigned* sg = staging + (size_t)b * CAP;
  int gb = b * CAP;   // windowed csr

  if (t < 256) cnt[t] = 0;
  __syncthreads();
  for (int i = t; i < ecnt; i += 1024) atomicAdd(&cnt[(sg[i] >> 17) & 255], 1);
  __syncthreads();
  int d = (t < 256) ? cnt[t] : 0;
  for (int off = 1; off < 256; off <<= 1) {
    int x = 0, y = 0;
    if (t < 256) { x = cnt[t]; y = (t >= off) ? cnt[t - off] : 0; }
    __syncthreads();
    if (t < 256) cnt[t] = x + y;
    __syncthreads();
  }
  if (t < 256) {
    int excl = cnt[t] - d;
    if (t < nrows) {
      rpd[r0 + t] = make_int2(gb + excl, d);
      dis[r0 + t] = rsqrtf(1.0f + (float)d);
    }
    cur[t] = excl;
  }
  __syncthreads();
  for (int i = t; i < ecnt; i += 1024) {
    unsigned p = sg[i];
    int j = atomicAdd(&cur[(p >> 17) & 255], 1);
    srt[j] = p & 0x1FFFFu;
  }
  __syncthreads();
  for (int i = t; i < ecnt; i += 1024)
    csr[gb + i] = (int)srt[i];
}

// ---- fused: tcol (blocks [0,nbuck)) || spmm one-wave-per-row (exact tails) ----
__global__ void __launch_bounds__(256) k_spmm(
    const u16* __restrict__ Xq,           // fp8 rows: 64 u16 per row (2 fp8 each)
    const int2* __restrict__ rpd,
    const float* __restrict__ dis,
    const int* __restrict__ csr,
    u16* __restrict__ z1h, int N,
    const unsigned* __restrict__ staging2,
    const int* __restrict__ bcount2P,
    float* __restrict__ tcol, int nbuck) {
  __shared__ float lacc[256];
  int blk = blockIdx.x;
  int t = threadIdx.x;

  if (blk < nbuck) {
    lacc[t] = 0.f;
    __syncthreads();
    int ecnt = bcount2P[blk * CPAD]; if (ecnt > CAP) ecnt = CAP;
    const unsigned* sg = staging2 + (size_t)blk * CAP;
    for (int i = t; i < ecnt; i += 256) {
      unsigned p = sg[i];
      atomicAdd(&lacc[(p >> 17) & 255], dis[p & 0x1FFFFu]);
    }
    __syncthreads();
    int c = (blk << BSH) + t;
    if (c < N) tcol[c] = lacc[t];
    return;
  }

  int wid = ((blk - nbuck) * 256 + t) >> 6;
  int rowi = __builtin_amdgcn_readfirstlane(wid);   // wave-uniform -> SGPR
  if (rowi >= N) return;
  int lane = t & 63;
  float dr = dis[rowi];
  u32 sv = Xq[(size_t)rowi * 64 + lane];
  float2 acc = make_float2(0.f, 0.f);
  int2 rd = rpd[rowi];
  int e0 = rd.x, e1 = rd.x + rd.y;
  int e = e0;
  for (; e + 16 <= e1; e += 16) {
    int c[16]; u32 v[16]; float w[16];
#pragma unroll
    for (int j = 0; j < 16; ++j) c[j] = csr[e + j];
#pragma unroll
    for (int j = 0; j < 16; ++j) v[j] = Xq[(size_t)c[j] * 64 + lane];
#pragma unroll
    for (int j = 0; j < 16; ++j) w[j] = dis[c[j]];
#pragma unroll
    for (int j = 0; j < 16; ++j) {
      float2 xv = fp8_dec2(v[j]);
      acc.x += w[j] * xv.x;
      acc.y += w[j] * xv.y;
    }
  }
  for (; e + 4 <= e1; e += 4) {
    int c[4]; u32 v[4]; float w[4];
#pragma unroll
    for (int j = 0; j < 4; ++j) c[j] = csr[e + j];
#pragma unroll
    for (int j = 0; j < 4; ++j) v[j] = Xq[(size_t)c[j] * 64 + lane];
#pragma unroll
    for (int j = 0; j < 4; ++j) w[j] = dis[c[j]];
#pragma unroll
    for (int j = 0; j < 4; ++j) {
      float2 xv = fp8_dec2(v[j]);
      acc.x += w[j] * xv.x;
      acc.y += w[j] * xv.y;
    }
  }
  for (; e < e1; ++e) {
    int c = csr[e];
    float w = dis[c];
    float2 xv = fp8_dec2(Xq[(size_t)c * 64 + lane]);
    acc.x += w * xv.x;
    acc.y += w * xv.y;
  }
  float2 sf = fp8_dec2(sv);
  acc.x = dr * (acc.x + dr * sf.x);
  acc.y = dr * (acc.y + dr * sf.y);
  ((u32*)(z1h + (size_t)rowi * F))[lane] = bf16_rne(acc.x) | (bf16_rne(acc.y) << 16);
}

// ---------------- MFMA GEMM, grid-stride, register partials, NO atomics ----------------
__global__ void __launch_bounds__(256) k_gemm_red(
    const u16* __restrict__ z1h,
    const u16* __restrict__ W1T,
    const float* __restrict__ b1,
    const float* __restrict__ dis,
    const float* __restrict__ tcol,
    float* __restrict__ partials, int N, int ntiles) {
  __shared__ float smat[16][128];
  int t = threadIdx.x;
  int w = t >> 6;
  int l = t & 63;
  int lr = l & 15;
  int lg = l >> 4;
  const u16* bbase = W1T + (size_t)lr * 128 + lg * 8;

  float psum[8] = {};

  for (int tile = blockIdx.x; tile < ntiles; tile += gridDim.x) {
    int g0 = tile * 64;
    int garow = g0 + 16 * w + lr;
    if (garow >= N) garow = N - 1;
    const u16* arow = z1h + (size_t)garow * F + lg * 8;
    short8 afr[4];
#pragma unroll
    for (int kb = 0; kb < 4; ++kb)
      afr[kb] = *(const short8*)(arow + kb * 32);

    float cw[4];
#pragma unroll
    for (int j = 0; j < 4; ++j) {
      int g = g0 + 16 * w + lg * 4 + j;
      float c = 0.f;
      if (g < N) { float dv = dis[g]; c = dv * (dv + tcol[g]); }
      cw[j] = c;
    }

#pragma unroll
    for (int n = 0; n < 8; ++n) {
      f32x4 acc = {0.f, 0.f, 0.f, 0.f};
      const u16* bp = bbase + (size_t)(16 * n) * 128;
#pragma unroll
      for (int kb = 0; kb < 4; ++kb) {
        short8 bfr = *(const short8*)(bp + kb * 32);
        acc = __builtin_amdgcn_mfma_f32_16x16x32_bf16(afr[kb], bfr, acc, 0, 0, 0);
      }
      float bb = b1[16 * n + lr];
      float p = 0.f;
#pragma unroll
      for (int j = 0; j < 4; ++j) {
        float h = acc[j] + bb;
        h = h > 0.f ? h : 0.f;
        p += cw[j] * h;
      }
      psum[n] += p;
    }
  }

#pragma unroll
  for (int n = 0; n < 8; ++n) smat[4 * w + lg][16 * n + lr] = psum[n];
  __syncthreads();
  if (t < F) {
    float v = 0.f;
#pragma unroll
    for (int i = 0; i < 16; ++i) v += smat[i][t];
    partials[blockIdx.x * F + t] = v;
  }
}

// ---- finalize (1024 thr, 8-deep unrolled): s = sum partials; out = (s/N)@W2 + b2 ----
__global__ void __launch_bounds__(1024) k_finish(
    const float* __restrict__ partials, int nblk,
    const float* __restrict__ W2, const float* __restrict__ b2,
    float* __restrict__ out, float invN) {
  __shared__ float red[8][F];
  int t = threadIdx.x;          // 1024 threads
  int q = t >> 7, c = t & 127;  // 8 row-groups x 128 cols
  float v = 0.f;
#pragma unroll 8
  for (int b = q; b < nblk; b += 8) v += partials[b * F + c];
  red[q][c] = v;
  __syncthreads();
  if (t < F) {
    float s = 0.f;
#pragma unroll
    for (int i = 0; i < 8; ++i) s += red[i][t];
    red[0][t] = s * invN;
  }
  __syncthreads();
  if (t < COUT) {
    float acc = b2[t];
#pragma unroll
    for (int k = 0; k < F; ++k) acc += red[0][k] * W2[k * COUT + t];
    out[t] = acc;
  }
}

extern "C" void kernel_launch(void* const* d_in, const int* in_sizes, int n_in,
                              void* d_out, int out_size, void* d_ws, size_t ws_size,
                              hipStream_t stream) {
  const int* edge = (const int*)d_in[0];
  const float* X  = (const float*)d_in[1];
  const float* W1 = (const float*)d_in[2];
  const float* b1 = (const float*)d_in[3];
  const float* W2 = (const float*)d_in[4];
  const float* b2 = (const float*)d_in[5];
  float* out = (float*)d_out;

  int E = in_sizes[0] / 2;
  int N = in_sizes[1] / F;
  const int* row = edge;
  const int* col = edge + E;
  int nbuck = (N + 255) >> BSH;
  int ntiles = (N + 63) / 64;
  int nbB = (E + CH - 1) / CH;
  int nvec = (N * F) / 8;
  int ncast = (nvec + 511) / 512;

  char* w = (char*)d_ws;
  auto alloc = [&](size_t bytes) {
    char* p = w;
    w += (bytes + 255) & ~(size_t)255;
    return p;
  };
  float*    tcol     = (float*)alloc((size_t)N * 4);
  float*    dis      = (float*)alloc((size_t)N * 4);
  int2*     rpd      = (int2*)alloc((size_t)N * 8);
  float*    partials = (float*)alloc((size_t)NBLK * F * 4);
  int*      bcountP  = (int*)alloc((size_t)512 * CPAD * 4);
  int*      bcount2P = (int*)alloc((size_t)512 * CPAD * 4);
  u16*      Xq       = (u16*)alloc((size_t)N * F);
  u16*      W1T      = (u16*)alloc((size_t)F * F * 2);
  unsigned* staging  = (unsigned*)alloc((size_t)nbuck * CAP * 4);
  unsigned* staging2 = (unsigned*)alloc((size_t)nbuck * CAP * 4);
  int*      csr      = (int*)alloc((size_t)nbuck * CAP * 4);
  u16*      z1h      = (u16*)alloc((size_t)N * F * 2);

  int nzero = 512 * CPAD;

  k_zero  <<<(nzero + 255) / 256, 256, 0, stream>>>(bcountP, bcount2P, nzero);
  k_fat1  <<<nbB + 32 + ncast, 512, 0, stream>>>(row, col, E, bcountP, staging,
                                                 bcount2P, staging2, nbuck, nbB,
                                                 (const float4*)X, (uint2*)Xq, nvec,
                                                 W1, W1T);
  k_build <<<nbuck, 1024, 0, stream>>>(staging, bcountP, rpd, dis, csr, N);
  k_spmm  <<<nbuck + (N + 3) / 4, 256, 0, stream>>>(Xq, rpd, dis, csr, z1h, N,
                                                    staging2, bcount2P, tcol, nbuck);
  k_gemm_red<<<NBLK, 256, 0, stream>>>(z1h, W1T, b1, dis, tcol, partials, N, ntiles);
  k_finish<<<1, 1024, 0, stream>>>(partials, NBLK, W2, b2, out, 1.0f / (float)N);
}

// Round 22
// 116.615 us; speedup vs baseline: 1.1850x; 1.1850x over previous
//
#include <hip/hip_runtime.h>
#include <hip/hip_fp8.h>

#define F 128      // F_IN == H == 128
#define COUT 40
#define BSH 8      // 256 rows/cols per bucket
#define CAP 6144   // staging/csr slots per bucket
#define CH 8192    // edges per bucket-block in k_fat1
#define EPT 16     // edges per thread (CH/512)
#define NBLK 512   // blocks for k_gemm_red
#define CPAD 32    // ints per counter (128 B line)

typedef unsigned int  u32;
typedef unsigned short u16;
typedef __attribute__((ext_vector_type(8))) short short8;
typedef __attribute__((ext_vector_type(4))) float f32x4;

__device__ inline u32 bf16_rne(float f) {
  u32 u = __float_as_uint(f);
  u += 0x7FFFu + ((u >> 16) & 1u);
  return u >> 16;
}

#if defined(__has_builtin)
#if __has_builtin(__builtin_amdgcn_cvt_pk_fp8_f32) && __has_builtin(__builtin_amdgcn_cvt_f32_fp8)
#define HAS_FP8_BUILTIN 1
#endif
#endif

__device__ inline u32 fp8_pk4(float4 a) {
#ifdef HAS_FP8_BUILTIN
  u32 v = (u32)__builtin_amdgcn_cvt_pk_fp8_f32(a.x, a.y, 0, false);
  v = (u32)__builtin_amdgcn_cvt_pk_fp8_f32(a.z, a.w, (int)v, true);
  return v;
#else
  __hip_fp8x2_e4m3 lo(float2{a.x, a.y});
  __hip_fp8x2_e4m3 hi(float2{a.z, a.w});
  return (u32)lo.__x | ((u32)hi.__x << 16);
#endif
}

__device__ inline float2 fp8_dec2(u32 v) {
#ifdef HAS_FP8_BUILTIN
  return make_float2(__builtin_amdgcn_cvt_f32_fp8(v, 0),
                     __builtin_amdgcn_cvt_f32_fp8(v, 1));
#else
  __hip_fp8x2_e4m3 p;
  p.__x = (__hip_fp8x2_storage_t)(v & 0xFFFFu);
  float2 f = (float2)p;
  return make_float2(f.x, f.y);
#endif
}

// ---------------- zero padded bucket counters ----------------
__global__ void k_zero(int* __restrict__ bcountP, int* __restrict__ bcount2P, int n) {
  int i = blockIdx.x * blockDim.x + threadIdx.x;
  if (i < n) { bcountP[i] = 0; bcount2P[i] = 0; }
}

// ---- fat1: one-pass dual bucket+LDS-sort (blocks [0,nbB)) || wt (32) || cast (rest) ----
// payload: bits 0-16 = other node, 17-24 = key&255, 25-31 = bucket&127
__global__ void __launch_bounds__(512) k_fat1(
    const int* __restrict__ row, const int* __restrict__ col, int E,
    int* __restrict__ bcountP, unsigned* __restrict__ staging,
    int* __restrict__ bcount2P, unsigned* __restrict__ staging2,
    int nbuck, int nbB,
    const float4* __restrict__ X, uint2* __restrict__ Xq, int nvec,
    const float* __restrict__ W1, u16* __restrict__ W1T) {
  __shared__ u32 pay1[CH];     // 32 KB
  __shared__ u32 pay2[CH];     // 32 KB
  __shared__ int hist1[512];
  __shared__ int hist2[512];
  __shared__ int lcur1[512];
  __shared__ int lcur2[512];
  __shared__ int gdelta1[512];
  __shared__ int gdelta2[512];
  int b = blockIdx.x;
  int t = threadIdx.x;

  if (b < nbB) {
    int base = b * CH;
    int n = E - base; if (n > CH) n = CH;
    int r[EPT], c[EPT];
#pragma unroll
    for (int j = 0; j < EPT; ++j) {
      int i = t + j * 512;
      if (i < n) { r[j] = row[base + i]; c[j] = col[base + i]; }
      else       { r[j] = -1; c[j] = -1; }
    }
    hist1[t] = 0; hist2[t] = 0;
    __syncthreads();
#pragma unroll
    for (int j = 0; j < EPT; ++j) if (r[j] >= 0) {
      atomicAdd(&hist1[r[j] >> BSH], 1);
      atomicAdd(&hist2[c[j] >> BSH], 1);
    }
    __syncthreads();
    int h1 = hist1[t], h2 = hist2[t];
    for (int off = 1; off < 512; off <<= 1) {
      int x1 = hist1[t], x2 = hist2[t];
      int y1 = (t >= off) ? hist1[t - off] : 0;
      int y2 = (t >= off) ? hist2[t - off] : 0;
      __syncthreads();
      hist1[t] = x1 + y1; hist2[t] = x2 + y2;
      __syncthreads();
    }
    if (t < nbuck) {
      int e1 = hist1[t] - h1, e2 = hist2[t] - h2;
      int s1 = (h1 > 0) ? atomicAdd(&bcountP[t * CPAD], h1) : 0;
      int s2 = (h2 > 0) ? atomicAdd(&bcount2P[t * CPAD], h2) : 0;
      gdelta1[t] = t * CAP + s1 - e1;
      gdelta2[t] = t * CAP + s2 - e2;
      lcur1[t] = e1; lcur2[t] = e2;
    }
    __syncthreads();
#pragma unroll
    for (int j = 0; j < EPT; ++j) if (r[j] >= 0) {
      int bk = r[j] >> BSH;
      int s = atomicAdd(&lcur1[bk], 1);
      pay1[s] = ((u32)(bk & 127) << 25) | ((u32)(r[j] & 255) << 17) | (u32)c[j];
      int bk2 = c[j] >> BSH;
      int s2 = atomicAdd(&lcur2[bk2], 1);
      pay2[s2] = ((u32)(bk2 & 127) << 25) | ((u32)(c[j] & 255) << 17) | (u32)r[j];
    }
    __syncthreads();
    int q1a = hist1[127], q1b = hist1[255], q1c = hist1[383];
    int q2a = hist2[127], q2b = hist2[255], q2c = hist2[383];
#pragma unroll
    for (int j = 0; j < EPT; ++j) {
      int i = t + j * 512;
      if (i < n) {
        u32 p = pay1[i];
        int bk = (((i >= q1a) + (i >= q1b) + (i >= q1c)) << 7) | (int)(p >> 25);
        int dst = i + gdelta1[bk];
        if (dst < (bk + 1) * CAP) staging[dst] = p;
        u32 p2 = pay2[i];
        int bk2 = (((i >= q2a) + (i >= q2b) + (i >= q2c)) << 7) | (int)(p2 >> 25);
        int dst2 = i + gdelta2[bk2];
        if (dst2 < (bk2 + 1) * CAP) staging2[dst2] = p2;
      }
    }
  } else if (b < nbB + 32) {
    int i = (b - nbB) * 512 + t;
    int k = i >> 7, nn = i & 127;
    W1T[nn * 128 + k] = (u16)bf16_rne(W1[i]);
  } else {
    int i = (b - nbB - 32) * 512 + t;
    if (i < nvec) {
      float4 a = X[2 * i], v = X[2 * i + 1];
      uint2 o;
      o.x = fp8_pk4(a);
      o.y = fp8_pk4(v);
      Xq[i] = o;
    }
  }
}

// ---- build: per-bucket CSR via LDS sort, coalesced csr writes, windowed ----
__global__ void __launch_bounds__(1024) k_build(
    const unsigned* __restrict__ staging,
    const int* __restrict__ bcountP,
    int2* __restrict__ rpd, float* __restrict__ dis,
    int* __restrict__ csr, int N) {
  __shared__ int cnt[256];
  __shared__ int cur[256];
  __shared__ u32 srt[CAP];   // 24 KB
  int b = blockIdx.x;
  int t = threadIdx.x;
  int r0 = b << BSH;
  int nrows = N - r0; if (nrows > 256) nrows = 256;
  int ecnt = bcountP[b * CPAD]; if (ecnt > CAP) ecnt = CAP;
  const unsigned* sg = staging + (size_t)b * CAP;
  int gb = b * CAP;   // windowed csr

  if (t < 256) cnt[t] = 0;
  __syncthreads();
  for (int i = t; i < ecnt; i += 1024) atomicAdd(&cnt[(sg[i] >> 17) & 255], 1);
  __syncthreads();
  int d = (t < 256) ? cnt[t] : 0;
  for (int off = 1; off < 256; off <<= 1) {
    int x = 0, y = 0;
    if (t < 256) { x = cnt[t]; y = (t >= off) ? cnt[t - off] : 0; }
    __syncthreads();
    if (t < 256) cnt[t] = x + y;
    __syncthreads();
  }
  if (t < 256) {
    int excl = cnt[t] - d;
    if (t < nrows) {
      rpd[r0 + t] = make_int2(gb + excl, d);
      dis[r0 + t] = rsqrtf(1.0f + (float)d);
    }
    cur[t] = excl;
  }
  __syncthreads();
  for (int i = t; i < ecnt; i += 1024) {
    unsigned p = sg[i];
    int j = atomicAdd(&cur[(p >> 17) & 255], 1);
    srt[j] = p & 0x1FFFFu;
  }
  __syncthreads();
  for (int i = t; i < ecnt; i += 1024)
    csr[gb + i] = (int)srt[i];
}

// ---- fused: tcol (blocks [0,nbuck)) || spmm one-wave-per-row (exact tails) ----
__global__ void __launch_bounds__(256) k_spmm(
    const u16* __restrict__ Xq,           // fp8 rows: 64 u16 per row (2 fp8 each)
    const int2* __restrict__ rpd,
    const float* __restrict__ dis,
    const int* __restrict__ csr,
    u16* __restrict__ z1h, int N,
    const unsigned* __restrict__ staging2,
    const int* __restrict__ bcount2P,
    float* __restrict__ tcol, int nbuck) {
  __shared__ float lacc[256];
  int blk = blockIdx.x;
  int t = threadIdx.x;

  if (blk < nbuck) {
    lacc[t] = 0.f;
    __syncthreads();
    int ecnt = bcount2P[blk * CPAD]; if (ecnt > CAP) ecnt = CAP;
    const unsigned* sg = staging2 + (size_t)blk * CAP;
    for (int i = t; i < ecnt; i += 256) {
      unsigned p = sg[i];
      atomicAdd(&lacc[(p >> 17) & 255], dis[p & 0x1FFFFu]);
    }
    __syncthreads();
    int c = (blk << BSH) + t;
    if (c < N) tcol[c] = lacc[t];
    return;
  }

  int wid = ((blk - nbuck) * 256 + t) >> 6;
  int rowi = __builtin_amdgcn_readfirstlane(wid);   // wave-uniform -> SGPR
  if (rowi >= N) return;
  int lane = t & 63;
  float dr = dis[rowi];
  u32 sv = Xq[(size_t)rowi * 64 + lane];
  float2 acc = make_float2(0.f, 0.f);
  int2 rd = rpd[rowi];
  int e0 = rd.x, e1 = rd.x + rd.y;
  int e = e0;
  for (; e + 16 <= e1; e += 16) {
    int c[16]; u32 v[16]; float w[16];
#pragma unroll
    for (int j = 0; j < 16; ++j) c[j] = csr[e + j];
#pragma unroll
    for (int j = 0; j < 16; ++j) v[j] = Xq[(size_t)c[j] * 64 + lane];
#pragma unroll
    for (int j = 0; j < 16; ++j) w[j] = dis[c[j]];
#pragma unroll
    for (int j = 0; j < 16; ++j) {
      float2 xv = fp8_dec2(v[j]);
      acc.x += w[j] * xv.x;
      acc.y += w[j] * xv.y;
    }
  }
  for (; e + 4 <= e1; e += 4) {
    int c[4]; u32 v[4]; float w[4];
#pragma unroll
    for (int j = 0; j < 4; ++j) c[j] = csr[e + j];
#pragma unroll
    for (int j = 0; j < 4; ++j) v[j] = Xq[(size_t)c[j] * 64 + lane];
#pragma unroll
    for (int j = 0; j < 4; ++j) w[j] = dis[c[j]];
#pragma unroll
    for (int j = 0; j < 4; ++j) {
      float2 xv = fp8_dec2(v[j]);
      acc.x += w[j] * xv.x;
      acc.y += w[j] * xv.y;
    }
  }
  for (; e < e1; ++e) {
    int c = csr[e];
    float w = dis[c];
    float2 xv = fp8_dec2(Xq[(size_t)c * 64 + lane]);
    acc.x += w * xv.x;
    acc.y += w * xv.y;
  }
  float2 sf = fp8_dec2(sv);
  acc.x = dr * (acc.x + dr * sf.x);
  acc.y = dr * (acc.y + dr * sf.y);
  ((u32*)(z1h + (size_t)rowi * F))[lane] = bf16_rne(acc.x) | (bf16_rne(acc.y) << 16);
}

// ---------------- MFMA GEMM, grid-stride, register partials, NO atomics ----------------
__global__ void __launch_bounds__(256) k_gemm_red(
    const u16* __restrict__ z1h,
    const u16* __restrict__ W1T,
    const float* __restrict__ b1,
    const float* __restrict__ dis,
    const float* __restrict__ tcol,
    float* __restrict__ partials, int N, int ntiles) {
  __shared__ float smat[16][128];
  int t = threadIdx.x;
  int w = t >> 6;
  int l = t & 63;
  int lr = l & 15;
  int lg = l >> 4;
  const u16* bbase = W1T + (size_t)lr * 128 + lg * 8;

  float psum[8] = {};

  for (int tile = blockIdx.x; tile < ntiles; tile += gridDim.x) {
    int g0 = tile * 64;
    int garow = g0 + 16 * w + lr;
    if (garow >= N) garow = N - 1;
    const u16* arow = z1h + (size_t)garow * F + lg * 8;
    short8 afr[4];
#pragma unroll
    for (int kb = 0; kb < 4; ++kb)
      afr[kb] = *(const short8*)(arow + kb * 32);

    float cw[4];
#pragma unroll
    for (int j = 0; j < 4; ++j) {
      int g = g0 + 16 * w + lg * 4 + j;
      float c = 0.f;
      if (g < N) { float dv = dis[g]; c = dv * (dv + tcol[g]); }
      cw[j] = c;
    }

#pragma unroll
    for (int n = 0; n < 8; ++n) {
      f32x4 acc = {0.f, 0.f, 0.f, 0.f};
      const u16* bp = bbase + (size_t)(16 * n) * 128;
#pragma unroll
      for (int kb = 0; kb < 4; ++kb) {
        short8 bfr = *(const short8*)(bp + kb * 32);
        acc = __builtin_amdgcn_mfma_f32_16x16x32_bf16(afr[kb], bfr, acc, 0, 0, 0);
      }
      float bb = b1[16 * n + lr];
      float p = 0.f;
#pragma unroll
      for (int j = 0; j < 4; ++j) {
        float h = acc[j] + bb;
        h = h > 0.f ? h : 0.f;
        p += cw[j] * h;
      }
      psum[n] += p;
    }
  }

#pragma unroll
  for (int n = 0; n < 8; ++n) smat[4 * w + lg][16 * n + lr] = psum[n];
  __syncthreads();
  if (t < F) {
    float v = 0.f;
#pragma unroll
    for (int i = 0; i < 16; ++i) v += smat[i][t];
    partials[blockIdx.x * F + t] = v;
  }
}

// ---- finalize (1024 thr, 8-deep unrolled): s = sum partials; out = (s/N)@W2 + b2 ----
__global__ void __launch_bounds__(1024) k_finish(
    const float* __restrict__ partials, int nblk,
    const float* __restrict__ W2, const float* __restrict__ b2,
    float* __restrict__ out, float invN) {
  __shared__ float red[8][F];
  int t = threadIdx.x;          // 1024 threads
  int q = t >> 7, c = t & 127;  // 8 row-groups x 128 cols
  float v = 0.f;
#pragma unroll 8
  for (int b = q; b < nblk; b += 8) v += partials[b * F + c];
  red[q][c] = v;
  __syncthreads();
  if (t < F) {
    float s = 0.f;
#pragma unroll
    for (int i = 0; i < 8; ++i) s += red[i][t];
    red[0][t] = s * invN;
  }
  __syncthreads();
  if (t < COUT) {
    float acc = b2[t];
#pragma unroll
    for (int k = 0; k < F; ++k) acc += red[0][k] * W2[k * COUT + t];
    out[t] = acc;
  }
}

extern "C" void kernel_launch(void* const* d_in, const int* in_sizes, int n_in,
                              void* d_out, int out_size, void* d_ws, size_t ws_size,
                              hipStream_t stream) {
  const int* edge = (const int*)d_in[0];
  const float* X  = (const float*)d_in[1];
  const float* W1 = (const float*)d_in[2];
  const float* b1 = (const float*)d_in[3];
  const float* W2 = (const float*)d_in[4];
  const float* b2 = (const float*)d_in[5];
  float* out = (float*)d_out;

  int E = in_sizes[0] / 2;
  int N = in_sizes[1] / F;
  const int* row = edge;
  const int* col = edge + E;
  int nbuck = (N + 255) >> BSH;
  int ntiles = (N + 63) / 64;
  int nbB = (E + CH - 1) / CH;
  int nvec = (N * F) / 8;
  int ncast = (nvec + 511) / 512;

  char* w = (char*)d_ws;
  auto alloc = [&](size_t bytes) {
    char* p = w;
    w += (bytes + 255) & ~(size_t)255;
    return p;
  };
  float*    tcol     = (float*)alloc((size_t)N * 4);
  float*    dis      = (float*)alloc((size_t)N * 4);
  int2*     rpd      = (int2*)alloc((size_t)N * 8);
  float*    partials = (float*)alloc((size_t)NBLK * F * 4);
  int*      bcountP  = (int*)alloc((size_t)512 * CPAD * 4);
  int*      bcount2P = (int*)alloc((size_t)512 * CPAD * 4);
  u16*      Xq       = (u16*)alloc((size_t)N * F);
  u16*      W1T      = (u16*)alloc((size_t)F * F * 2);
  unsigned* staging  = (unsigned*)alloc((size_t)nbuck * CAP * 4);
  unsigned* staging2 = (unsigned*)alloc((size_t)nbuck * CAP * 4);
  int*      csr      = (int*)alloc((size_t)nbuck * CAP * 4);
  u16*      z1h      = (u16*)alloc((size_t)N * F * 2);

  int nzero = 512 * CPAD;

  k_zero  <<<(nzero + 255) / 256, 256, 0, stream>>>(bcountP, bcount2P, nzero);
  k_fat1  <<<nbB + 32 + ncast, 512, 0, stream>>>(row, col, E, bcountP, staging,
                                                 bcount2P, staging2, nbuck, nbB,
                                                 (const float4*)X, (uint2*)Xq, nvec,
                                                 W1, W1T);
  k_build <<<nbuck, 1024, 0, stream>>>(staging, bcountP, rpd, dis, csr, N);
  k_spmm  <<<nbuck + (N + 3) / 4, 256, 0, stream>>>(Xq, rpd, dis, csr, z1h, N,
                                                    staging2, bcount2P, tcol, nbuck);
  k_gemm_red<<<NBLK, 256, 0, stream>>>(z1h, W1T, b1, dis, tcol, partials, N, ntiles);
  k_finish<<<1, 1024, 0, stream>>>(partials, NBLK, W2, b2, out, 1.0f / (float)N);
}